// Round 2
// baseline (989.814 us; speedup 1.0000x reference)
//
#include <hip/hip_runtime.h>
#include <math.h>

// Problem constants (from reference)
#define Bn    256
#define Tn    1024
#define In    64
#define Pn    256
#define En    128
#define NOUTn 64
#define LN_EPS 1e-5f
#define TEMPc  8.0f

// ============================================================================
// DPP wave-64 sum (canonical gfx9 sequence, result broadcast via readlane 63).
// VALU-latency cross-lane reduce: ~6x8 cycles vs ~6x(40..120) for ds_swizzle.
// ============================================================================
template<int CTRL, int RMASK>
__device__ __forceinline__ float dpp_add(float x) {
    return x + __int_as_float(__builtin_amdgcn_update_dpp(
        0, __float_as_int(x), CTRL, RMASK, 0xF, false));
}
__device__ __forceinline__ float wave_sum64(float x) {
    x = dpp_add<0x111, 0xF>(x);   // row_shr:1
    x = dpp_add<0x112, 0xF>(x);   // row_shr:2
    x = dpp_add<0x114, 0xF>(x);   // row_shr:4
    x = dpp_add<0x118, 0xF>(x);   // row_shr:8
    x = dpp_add<0x142, 0xA>(x);   // row_bcast:15 -> rows 1,3
    x = dpp_add<0x143, 0xC>(x);   // row_bcast:31 -> rows 2,3
    return __int_as_float(__builtin_amdgcn_readlane(__float_as_int(x), 63));
}

// ============================================================================
// Pass A: emb[b,t,e] = tanh(x[b,t,:] . W_in[e,:] + b_in[e])  (scan-independent)
// Memory-bound: reads 64MB x, writes 128MB emb.
// Block = 256 threads handles (b, 8 timesteps); grid = 256*128.
// ============================================================================
__global__ __launch_bounds__(256, 4)
void emb_kernel(const float* __restrict__ x, const float* __restrict__ W_in,
                const float* __restrict__ b_in, float* __restrict__ emb) {
    __shared__ float xt[8 * In];            // 2 KB x tile
    const int blk = blockIdx.x;
    const int b   = blk >> 7;               // / 128
    const int t0  = (blk & 127) << 3;       // * 8
    const int tid = threadIdx.x;
    const float* xsrc = x + ((size_t)b * Tn + t0) * In;
    xt[tid]       = xsrc[tid];
    xt[256 + tid] = xsrc[256 + tid];

    const int e   = tid & 127;
    const int tl0 = tid >> 7;               // 0 or 1
    float w[In];
    {
        const float4* w4 = (const float4*)(W_in + e * In);
        #pragma unroll
        for (int i = 0; i < 16; ++i) {
            float4 v = w4[i];
            w[4*i] = v.x; w[4*i+1] = v.y; w[4*i+2] = v.z; w[4*i+3] = v.w;
        }
    }
    const float be = b_in[e];
    __syncthreads();

    #pragma unroll
    for (int k = 0; k < 4; ++k) {
        const int tl = tl0 + 2 * k;
        const float* xr = xt + tl * In;
        float a0 = 0.f, a1 = 0.f, a2 = 0.f, a3 = 0.f;
        #pragma unroll
        for (int i = 0; i < In; i += 4) {
            a0 += w[i]   * xr[i];
            a1 += w[i+1] * xr[i+1];
            a2 += w[i+2] * xr[i+2];
            a3 += w[i+3] * xr[i+3];
        }
        emb[((size_t)b * Tn + t0 + tl) * En + e] = tanhf((a0 + a1) + (a2 + a3) + be);
    }
}

// ============================================================================
// Pass B: the sequential scan. ONE WAVE per batch -> no barriers at all.
// Ring memory (128 KB) lives in LDS, column e owned by one lane (no conflicts,
// no sync). emb[t] comes from global with a 2-step register prefetch.
// ============================================================================
#define LDSG_FLOATS (Pn * En + Pn)
#define LDSG_BYTES  (LDSG_FLOATS * 4)

__global__ __launch_bounds__(64, 1)
void scan_kernel(const float* __restrict__ emb,
                 const float* __restrict__ pointer_init,
                 const float* __restrict__ ln_w, const float* __restrict__ ln_b,
                 const float* __restrict__ jump_dest,
                 const float* __restrict__ Wg,  const float* __restrict__ bg,
                 const float* __restrict__ cs_ptr,
                 const float* __restrict__ Wo,  const float* __restrict__ bo,
                 float* __restrict__ out) {
    extern __shared__ float lds[];
    float* mem = lds;              // Pn*En ring memory
    float* jd  = lds + Pn * En;    // jump_dest copy

    const int b = blockIdx.x;
    const int l = threadIdx.x;

    float4* m4 = (float4*)mem;
    for (int i = l; i < Pn * En / 4; i += 64) m4[i] = make_float4(0.f, 0.f, 0.f, 0.f);
    for (int i = l; i < Pn; i += 64) jd[i] = jump_dest[i];

    const float lnw0 = ln_w[l], lnw1 = ln_w[l + 64];
    const float lnb0 = ln_b[l], lnb1 = ln_b[l + 64];
    const float wg0  = Wg[l],   wg1  = Wg[l + 64];
    const float bgs  = bg[0];
    const float cs   = 1.0f / (1.0f + expf(-cs_ptr[0]));
    float hid0 = 0.f, hid1 = 0.f;
    float ptr  = pointer_init[b];

    const float* erow = emb + (size_t)b * Tn * En;
    float c0 = erow[l],      c1 = erow[64 + l];        // emb[0]
    float n0 = erow[En + l], n1 = erow[En + 64 + l];   // emb[1]

    for (int t = 0; t < Tn; ++t) {
        // prefetch emb[t+2] (covered by ~2 full steps of latency)
        float f0 = 0.f, f1 = 0.f;
        if (t + 2 < Tn) {
            const float* er = erow + (size_t)(t + 2) * En;
            f0 = er[l]; f1 = er[64 + l];
        }

        // jump target: cur known at step top, jt consumed at step bottom
        int cur = (int)ptr; cur = cur < 0 ? 0 : (cur > Pn - 1 ? Pn - 1 : cur);
        const float jt = jd[cur];

        int base = (int)floorf(ptr);
        base = base < 0 ? 0 : (base > Pn - 1 ? Pn - 1 : base);
        const float frac = ptr - (float)base;           // exact

        int idx[5];
        #pragma unroll
        for (int j = 0; j < 5; ++j) idx[j] = (base + j - 2 + Pn) & (Pn - 1);

        // gather neighborhood first (ds_read2-pairable, longest latency)
        float nb0[5], nb1[5];
        #pragma unroll
        for (int j = 0; j < 5; ++j) {
            const float* p = mem + idx[j] * En + l;
            nb0[j] = p[0]; nb1[j] = p[64];
        }

        // softmax weights over delta = (j-2) - frac  (bit-exact vs ref's mod form)
        float wgt[5]; float mx = -3.4e38f;
        #pragma unroll
        for (int j = 0; j < 5; ++j) {
            float d = (float)(j - 2) - frac;
            float s = -(d * d) * (1.0f / TEMPc);
            wgt[j] = s; mx = fmaxf(mx, s);
        }
        float se = 0.f;
        #pragma unroll
        for (int j = 0; j < 5; ++j) { float ez = __expf(wgt[j] - mx); wgt[j] = ez; se += ez; }
        const float inv = 1.0f / se;
        #pragma unroll
        for (int j = 0; j < 5; ++j) wgt[j] *= inv;

        const float ctx0 = (wgt[0]*nb0[0] + wgt[1]*nb0[1]) + (wgt[2]*nb0[2] + wgt[3]*nb0[3]) + wgt[4]*nb0[4];
        const float ctx1 = (wgt[0]*nb1[0] + wgt[1]*nb1[1]) + (wgt[2]*nb1[2] + wgt[3]*nb1[3]) + wgt[4]*nb1[4];

        const float su0 = tanhf(c0 + cs * ctx0 + hid0);
        const float su1 = tanhf(c1 + cs * ctx1 + hid1);

        // fused scatter-add (indices distinct -> exact .at[].add; same-wave DS order)
        #pragma unroll
        for (int j = 0; j < 5; ++j) {
            float* p = mem + idx[j] * En + l;
            p[0]  = nb0[j] + wgt[j] * su0;
            p[64] = nb1[j] + wgt[j] * su1;
        }

        // three wave reductions at VALU latency
        const float s1 = wave_sum64(su0 + su1);
        const float s2 = wave_sum64(su0 * su0 + su1 * su1);
        const float s3 = wave_sum64(su0 * wg0 + su1 * wg1);

        const float mu   = s1 * (1.0f / En);
        const float var  = s2 * (1.0f / En) - mu * mu;
        const float rstd = rsqrtf(var + LN_EPS);
        hid0 = (su0 - mu) * rstd * lnw0 + lnb0;
        hid1 = (su1 - mu) * rstd * lnw1 + lnb1;

        // pointer update: sigmoid(jl) > 0.5  <=>  jl > 0 (uniform scalar)
        const float jl = s3 + bgs;
        float walk = ptr + 1.0f;
        if (walk >= 256.0f) walk -= 256.0f;
        ptr = (jl > 0.0f) ? jt : walk;

        c0 = n0; c1 = n1; n0 = f0; n1 = f1;   // rotate prefetch regs
    }

    // epilogue: logits = hid @ Wo^T + bo (reuse ring LDS for hid broadcast)
    mem[l] = hid0; mem[64 + l] = hid1;
    __syncthreads();   // single wave: just forces LDS visibility ordering
    const float4* w4 = (const float4*)(Wo + l * En);
    const float4* h4 = (const float4*)mem;
    float a0 = 0.f, a1 = 0.f, a2 = 0.f, a3 = 0.f;
    #pragma unroll
    for (int i = 0; i < En / 4; ++i) {
        float4 wv = w4[i]; float4 hv = h4[i];
        a0 += wv.x * hv.x; a1 += wv.y * hv.y; a2 += wv.z * hv.z; a3 += wv.w * hv.w;
    }
    out[b * NOUTn + l] = (a0 + a1) + (a2 + a3) + bo[l];
}

// ============================================================================
// Fallback (ws too small for the 128 MiB emb buffer): round-1 kernel, verbatim.
// ============================================================================
#define LDS_FLOATS (Pn*En + 2*En + 2*In + Pn)
#define LDS_BYTES  (LDS_FLOATS * 4)

__global__ __launch_bounds__(192, 1)
void ring_kernel(const float* __restrict__ x,
                 const float* __restrict__ pointer_init,
                 const float* __restrict__ W_in,
                 const float* __restrict__ b_in,
                 const float* __restrict__ ln_w,
                 const float* __restrict__ ln_b,
                 const float* __restrict__ jump_dest,
                 const float* __restrict__ Wg,
                 const float* __restrict__ bg,
                 const float* __restrict__ cs_ptr,
                 const float* __restrict__ Wo,
                 const float* __restrict__ bo,
                 float* __restrict__ out)
{
    extern __shared__ float lds[];
    float* mem  = lds;
    float* embb = mem + Pn * En;
    float* xb   = embb + 2 * En;
    float* jd   = xb + 2 * In;

    const int b   = blockIdx.x;
    const int tid = threadIdx.x;

    for (int i = tid; i < Pn * En; i += 192) mem[i] = 0.0f;
    for (int i = tid; i < Pn;      i += 192) jd[i]  = jump_dest[i];

    const float* xrow = x + (size_t)b * Tn * In;
    if (tid < 64) {
        xb[tid]      = xrow[tid];
        xb[In + tid] = xrow[In + tid];
    }
    __syncthreads();

    if (tid >= 64) {
        const int p = tid - 64;
        float wr[In];
        {
            const float4* w4 = (const float4*)(W_in + p * In);
            #pragma unroll
            for (int i = 0; i < In / 4; ++i) {
                float4 v = w4[i];
                wr[4*i+0] = v.x; wr[4*i+1] = v.y; wr[4*i+2] = v.z; wr[4*i+3] = v.w;
            }
        }
        const float bi = b_in[p];
        {
            float acc = bi;
            #pragma unroll
            for (int i = 0; i < In; ++i) acc += wr[i] * xb[i];
            embb[p] = tanhf(acc);
        }
        __syncthreads();
        for (int t = 0; t < Tn; ++t) {
            if (t + 1 < Tn) {
                const float* xc = xb + ((t + 1) & 1) * In;
                float acc = bi;
                #pragma unroll
                for (int i = 0; i < In; ++i) acc += wr[i] * xc[i];
                embb[((t + 1) & 1) * En + p] = tanhf(acc);
            }
            __syncthreads();
        }
    } else {
        const int l = tid;
        const float lnw0 = ln_w[l],      lnw1 = ln_w[l + 64];
        const float lnb0 = ln_b[l],      lnb1 = ln_b[l + 64];
        const float wg0  = Wg[l],        wg1  = Wg[l + 64];
        const float bgs  = bg[0];
        const float cs   = 1.0f / (1.0f + expf(-cs_ptr[0]));
        float hid0 = 0.0f, hid1 = 0.0f;
        float ptr  = pointer_init[b];
        __syncthreads();

        for (int t = 0; t < Tn; ++t) {
            const bool do_stage = (t + 2 < Tn);
            float xs = 0.0f;
            if (do_stage) xs = xrow[(t + 2) * In + l];

            const float* embc = embb + (t & 1) * En;

            int base = (int)floorf(ptr);
            base = base < 0 ? 0 : (base > Pn - 1 ? Pn - 1 : base);
            int cur = (int)ptr;
            cur = cur < 0 ? 0 : (cur > Pn - 1 ? Pn - 1 : cur);
            const float jt = jd[cur];

            const float frac = ptr - (float)base;
            int   idx[5];
            float wgt[5];
            float mx = -3.4e38f;
            #pragma unroll
            for (int j = 0; j < 5; ++j) {
                idx[j] = (base + j - 2 + Pn) & (Pn - 1);
                float d = (float)(j - 2) - frac;
                float s = -(d * d) * (1.0f / TEMPc);
                wgt[j] = s;
                mx = fmaxf(mx, s);
            }
            float se = 0.0f;
            #pragma unroll
            for (int j = 0; j < 5; ++j) { float ez = expf(wgt[j] - mx); wgt[j] = ez; se += ez; }
            const float inv = 1.0f / se;

            float nb0[5], nb1[5];
            #pragma unroll
            for (int j = 0; j < 5; ++j) {
                nb0[j] = mem[idx[j] * En + l];
                nb1[j] = mem[idx[j] * En + 64 + l];
            }
            float ctx0 = 0.0f, ctx1 = 0.0f;
            #pragma unroll
            for (int j = 0; j < 5; ++j) {
                const float w = wgt[j] * inv; wgt[j] = w;
                ctx0 += w * nb0[j];
                ctx1 += w * nb1[j];
            }

            const float su0 = tanhf(embc[l]      + cs * ctx0 + hid0);
            const float su1 = tanhf(embc[l + 64] + cs * ctx1 + hid1);

            #pragma unroll
            for (int j = 0; j < 5; ++j) {
                mem[idx[j] * En + l]      = nb0[j] + wgt[j] * su0;
                mem[idx[j] * En + 64 + l] = nb1[j] + wgt[j] * su1;
            }

            float s1 = su0 + su1;
            float s2 = su0 * su0 + su1 * su1;
            float s3 = su0 * wg0 + su1 * wg1;
            #pragma unroll
            for (int off = 32; off > 0; off >>= 1) {
                s1 += __shfl_xor(s1, off, 64);
                s2 += __shfl_xor(s2, off, 64);
                s3 += __shfl_xor(s3, off, 64);
            }

            const float mu   = s1 * (1.0f / En);
            const float var  = s2 * (1.0f / En) - mu * mu;
            const float rstd = rsqrtf(var + LN_EPS);
            hid0 = (su0 - mu) * rstd * lnw0 + lnb0;
            hid1 = (su1 - mu) * rstd * lnw1 + lnb1;

            const float jl = s3 + bgs;
            float walk = ptr + 1.0f;
            if (walk >= 256.0f) walk -= 256.0f;
            ptr = (jl > 0.0f) ? jt : walk;

            if (do_stage) xb[(t & 1) * In + l] = xs;
            __syncthreads();
        }
        embb[l]      = hid0;
        embb[l + 64] = hid1;
    }
    __syncthreads();

    if (tid < NOUTn) {
        const float* wrow = Wo + tid * En;
        float acc = bo[tid];
        #pragma unroll 4
        for (int e = 0; e < En; ++e) acc += embb[e] * wrow[e];
        out[b * NOUTn + tid] = acc;
    }
}

extern "C" void kernel_launch(void* const* d_in, const int* in_sizes, int n_in,
                              void* d_out, int out_size, void* d_ws, size_t ws_size,
                              hipStream_t stream) {
    const float* x            = (const float*)d_in[0];
    const float* pointer_init = (const float*)d_in[1];
    const float* W_in         = (const float*)d_in[2];
    const float* b_in         = (const float*)d_in[3];
    const float* ln_w         = (const float*)d_in[4];
    const float* ln_b         = (const float*)d_in[5];
    const float* jump_dest    = (const float*)d_in[6];
    const float* Wg           = (const float*)d_in[7];
    const float* bg           = (const float*)d_in[8];
    const float* cs           = (const float*)d_in[9];
    const float* Wo           = (const float*)d_in[10];
    const float* bo           = (const float*)d_in[11];
    float* out = (float*)d_out;

    const size_t emb_bytes = (size_t)Bn * Tn * En * sizeof(float);   // 128 MiB

    if (ws_size >= emb_bytes) {
        float* emb = (float*)d_ws;
        emb_kernel<<<Bn * 128, 256, 0, stream>>>(x, W_in, b_in, emb);
        (void)hipFuncSetAttribute((const void*)scan_kernel,
                                  hipFuncAttributeMaxDynamicSharedMemorySize, LDSG_BYTES);
        scan_kernel<<<Bn, 64, LDSG_BYTES, stream>>>(
            emb, pointer_init, ln_w, ln_b, jump_dest, Wg, bg, cs, Wo, bo, out);
    } else {
        (void)hipFuncSetAttribute((const void*)ring_kernel,
                                  hipFuncAttributeMaxDynamicSharedMemorySize, LDS_BYTES);
        ring_kernel<<<Bn, 192, LDS_BYTES, stream>>>(
            x, pointer_init, W_in, b_in, ln_w, ln_b, jump_dest, Wg, bg, cs, Wo, bo, out);
    }
}

// Round 3
// 777.946 us; speedup vs baseline: 1.2723x; 1.2723x over previous
//
#include <hip/hip_runtime.h>
#include <math.h>

// Problem constants (from reference)
#define Bn    256
#define Tn    1024
#define In    64
#define Pn    256
#define En    128
#define NOUTn 64
#define LN_EPS 1e-5f
#define TEMPc  8.0f

// ---------------------------------------------------------------------------
// Fast device math: single-instruction transcendentals (no libm branches).
// tanh(x) = 1 - 2/(exp2(2*log2e*x)+1). Saturates correctly at +-inf args.
// ---------------------------------------------------------------------------
__device__ __forceinline__ float tanh_fast(float x) {
    float e = __builtin_amdgcn_exp2f(x * 2.88539008177793f);   // e^(2x)
    return 1.0f - 2.0f * __builtin_amdgcn_rcpf(e + 1.0f);
}

// ---------------------------------------------------------------------------
// DPP wave-64 sum, 3 values interleaved (independent chains hide latency).
// ---------------------------------------------------------------------------
template<int CTRL, int RMASK>
__device__ __forceinline__ float dpp_add(float x) {
    return x + __int_as_float(__builtin_amdgcn_update_dpp(
        0, __float_as_int(x), CTRL, RMASK, 0xF, false));
}
__device__ __forceinline__ void wave_sum64_x3(float& x, float& y, float& z) {
#define LVL(C, R) x = dpp_add<C, R>(x); y = dpp_add<C, R>(y); z = dpp_add<C, R>(z);
    LVL(0x111, 0xF)   // row_shr:1
    LVL(0x112, 0xF)   // row_shr:2
    LVL(0x114, 0xF)   // row_shr:4
    LVL(0x118, 0xF)   // row_shr:8
    LVL(0x142, 0xA)   // row_bcast:15
    LVL(0x143, 0xC)   // row_bcast:31
#undef LVL
    x = __int_as_float(__builtin_amdgcn_readlane(__float_as_int(x), 63));
    y = __int_as_float(__builtin_amdgcn_readlane(__float_as_int(y), 63));
    z = __int_as_float(__builtin_amdgcn_readlane(__float_as_int(z), 63));
}

// ===========================================================================
// Pass A: emb4[b][t/4][e][t%4] = tanh(x[b,t,:] . W_in[e,:] + b_in[e])
// lane = channel; W row in 64 VGPRs (loaded once); x rows are wave-uniform
// -> scalar loads; zero LDS. Blocked layout so the scan reads 4 timesteps
// per channel with one dwordx4.
// Grid: Bn*4 blocks x 128 threads; each block: one b, 256 timesteps.
// ===========================================================================
__global__ __launch_bounds__(128, 1)
void emb4_kernel(const float* __restrict__ x, const float* __restrict__ W_in,
                 const float* __restrict__ b_in, float* __restrict__ emb4) {
    const int b  = blockIdx.x >> 2;
    const int tq = blockIdx.x & 3;          // timestep quarter
    const int e  = threadIdx.x;             // channel 0..127

    float w[In];
    {
        const float4* w4 = (const float4*)(W_in + e * In);
        #pragma unroll
        for (int i = 0; i < In / 4; ++i) {
            float4 v = w4[i];
            w[4*i] = v.x; w[4*i+1] = v.y; w[4*i+2] = v.z; w[4*i+3] = v.w;
        }
    }
    const float be = b_in[e];

    const float*  xrow = x + (((size_t)b * Tn) + (size_t)tq * 256) * In;
    float*        dst  = emb4 + ((size_t)b * 256 + (size_t)tq * 64) * 512 + e * 4;

    for (int tb = 0; tb < 64; ++tb) {
        float4 o;
        #pragma unroll
        for (int k = 0; k < 4; ++k) {
            // wave-uniform address -> scalar loads
            const float4* xr4 = (const float4*)(xrow + (tb * 4 + k) * In);
            float a0 = 0.f, a1 = 0.f, a2 = 0.f, a3 = 0.f;
            #pragma unroll
            for (int i = 0; i < In / 4; ++i) {
                float4 xv = xr4[i];
                a0 += xv.x * w[4*i];
                a1 += xv.y * w[4*i+1];
                a2 += xv.z * w[4*i+2];
                a3 += xv.w * w[4*i+3];
            }
            float acc = (a0 + a1) + (a2 + a3) + be;
            float* op = (float*)&o;
            op[k] = tanh_fast(acc);
        }
        *(float4*)dst = o;                  // 128 threads -> contiguous 2 KB
        dst += 512;
    }
}

// ===========================================================================
// Pass B: sequential scan, ONE WAVE per batch, no barriers in the loop.
// Ring memory (128 KB) in LDS, column e owned by one lane. emb consumed in
// 4-step blocks from the tb-blocked layout with ~8-11 step prefetch depth.
// ===========================================================================
#define LDSG_FLOATS (Pn * En + Pn)
#define LDSG_BYTES  (LDSG_FLOATS * 4)

__global__ __launch_bounds__(64, 1)
void scan2_kernel(const float* __restrict__ emb4,
                  const float* __restrict__ pointer_init,
                  const float* __restrict__ ln_w, const float* __restrict__ ln_b,
                  const float* __restrict__ jump_dest,
                  const float* __restrict__ Wg,  const float* __restrict__ bg,
                  const float* __restrict__ cs_ptr,
                  const float* __restrict__ Wo,  const float* __restrict__ bo,
                  float* __restrict__ out) {
    extern __shared__ float lds[];
    float* mem = lds;              // Pn*En ring memory
    float* jd  = lds + Pn * En;    // jump_dest copy

    const int b = blockIdx.x;
    const int l = threadIdx.x;

    float4* m4 = (float4*)mem;
    for (int i = l; i < Pn * En / 4; i += 64) m4[i] = make_float4(0.f, 0.f, 0.f, 0.f);
    for (int i = l; i < Pn; i += 64) jd[i] = jump_dest[i];

    const float lnw0 = ln_w[l], lnw1 = ln_w[l + 64];
    const float lnb0 = ln_b[l], lnb1 = ln_b[l + 64];
    const float wg0  = Wg[l],   wg1  = Wg[l + 64];
    const float bgs  = bg[0];
    const float cs   = 1.0f / (1.0f + expf(-cs_ptr[0]));
    float hid0 = 0.f, hid1 = 0.f;
    float ptr  = pointer_init[b];

    const float4* e40 = (const float4*)(emb4 + ((size_t)b << 17)) + l;       // ch l
    const float4* e41 = e40 + 64;                                            // ch l+64
    // prefetch blocks tb=0,1 (each float4 = 4 timesteps of one channel)
    float4 A0 = e40[0],   A1 = e41[0];
    float4 B0 = e40[128], B1 = e41[128];

    const float Cexp = -0.1803368801111204f;   // -log2(e)/8 (TEMP=8)

#define STEP(c0, c1) {                                                        \
    int base = (int)ptr;                                                      \
    base = base < 0 ? 0 : (base > Pn - 1 ? Pn - 1 : base);                    \
    const float jt   = jd[base];                                              \
    const float frac = ptr - (float)base;                                     \
    const int i0 = (base + 254) & 255, i1 = (base + 255) & 255;               \
    const int i3 = (base + 1) & 255,   i4 = (base + 2) & 255;                 \
    float* q0 = mem + (i0 << 7) + l;  float* q1 = mem + (i1 << 7) + l;        \
    float* q2 = mem + (base << 7) + l;                                        \
    float* q3 = mem + (i3 << 7) + l;  float* q4 = mem + (i4 << 7) + l;        \
    const float n00 = q0[0], n01 = q1[0], n02 = q2[0], n03 = q3[0], n04 = q4[0]; \
    const float n10 = q0[64], n11 = q1[64], n12 = q2[64], n13 = q3[64], n14 = q4[64]; \
    const float d0 = -2.f - frac, d1 = -1.f - frac, d2 = -frac,               \
                d3 = 1.f - frac,  d4 = 2.f - frac;                            \
    const float z0 = __builtin_amdgcn_exp2f(d0 * d0 * Cexp);                  \
    const float z1 = __builtin_amdgcn_exp2f(d1 * d1 * Cexp);                  \
    const float z2 = __builtin_amdgcn_exp2f(d2 * d2 * Cexp);                  \
    const float z3 = __builtin_amdgcn_exp2f(d3 * d3 * Cexp);                  \
    const float z4 = __builtin_amdgcn_exp2f(d4 * d4 * Cexp);                  \
    const float inv = __builtin_amdgcn_rcpf(((z0 + z1) + (z2 + z3)) + z4);    \
    const float ctx0 = inv * (((z0*n00 + z1*n01) + (z2*n02 + z3*n03)) + z4*n04); \
    const float ctx1 = inv * (((z0*n10 + z1*n11) + (z2*n12 + z3*n13)) + z4*n14); \
    const float su0 = tanh_fast((c0) + cs * ctx0 + hid0);                     \
    const float su1 = tanh_fast((c1) + cs * ctx1 + hid1);                     \
    const float g0 = inv * su0, g1 = inv * su1;                               \
    q0[0]  = n00 + z0 * g0;  q1[0]  = n01 + z1 * g0;  q2[0] = n02 + z2 * g0;  \
    q3[0]  = n03 + z3 * g0;  q4[0]  = n04 + z4 * g0;                          \
    q0[64] = n10 + z0 * g1;  q1[64] = n11 + z1 * g1;  q2[64] = n12 + z2 * g1; \
    q3[64] = n13 + z3 * g1;  q4[64] = n14 + z4 * g1;                          \
    float s1 = su0 + su1;                                                     \
    float s2 = su0 * su0 + su1 * su1;                                         \
    float s3 = su0 * wg0 + su1 * wg1;                                         \
    wave_sum64_x3(s1, s2, s3);                                                \
    const float mu   = s1 * (1.0f / En);                                      \
    const float var  = s2 * (1.0f / En) - mu * mu;                            \
    const float rstd = __builtin_amdgcn_rsqf(var + LN_EPS);                   \
    hid0 = (su0 - mu) * rstd * lnw0 + lnb0;                                   \
    hid1 = (su1 - mu) * rstd * lnw1 + lnb1;                                   \
    const float jl = s3 + bgs;                                                \
    float walk = ptr + 1.0f;                                                  \
    if (walk >= 256.0f) walk -= 256.0f;                                       \
    ptr = (jl > 0.0f) ? jt : walk;                                            \
}

    for (int tb = 0; tb < 256; ++tb) {
        const int tp = tb + 2 > 255 ? 255 : tb + 2;     // branch-free prefetch
        float4 C0 = e40[tp << 7];
        float4 C1 = e41[tp << 7];
        STEP(A0.x, A1.x)
        STEP(A0.y, A1.y)
        STEP(A0.z, A1.z)
        STEP(A0.w, A1.w)
        A0 = B0; A1 = B1; B0 = C0; B1 = C1;
    }
#undef STEP

    // epilogue: logits = hid @ Wo^T + bo
    mem[l] = hid0; mem[64 + l] = hid1;
    __syncthreads();
    const float4* w4 = (const float4*)(Wo + l * En);
    const float4* h4 = (const float4*)mem;
    float a0 = 0.f, a1 = 0.f, a2 = 0.f, a3 = 0.f;
    #pragma unroll
    for (int i = 0; i < En / 4; ++i) {
        float4 wv = w4[i]; float4 hv = h4[i];
        a0 += wv.x * hv.x; a1 += wv.y * hv.y; a2 += wv.z * hv.z; a3 += wv.w * hv.w;
    }
    out[b * NOUTn + l] = (a0 + a1) + (a2 + a3) + bo[l];
}

// ===========================================================================
// Fallback (ws too small for the 128 MiB emb buffer): round-1 kernel.
// ===========================================================================
#define LDS_FLOATS (Pn*En + 2*En + 2*In + Pn)
#define LDS_BYTES  (LDS_FLOATS * 4)

__global__ __launch_bounds__(192, 1)
void ring_kernel(const float* __restrict__ x,
                 const float* __restrict__ pointer_init,
                 const float* __restrict__ W_in,
                 const float* __restrict__ b_in,
                 const float* __restrict__ ln_w,
                 const float* __restrict__ ln_b,
                 const float* __restrict__ jump_dest,
                 const float* __restrict__ Wg,
                 const float* __restrict__ bg,
                 const float* __restrict__ cs_ptr,
                 const float* __restrict__ Wo,
                 const float* __restrict__ bo,
                 float* __restrict__ out)
{
    extern __shared__ float lds[];
    float* mem  = lds;
    float* embb = mem + Pn * En;
    float* xb   = embb + 2 * En;
    float* jd   = xb + 2 * In;

    const int b   = blockIdx.x;
    const int tid = threadIdx.x;

    for (int i = tid; i < Pn * En; i += 192) mem[i] = 0.0f;
    for (int i = tid; i < Pn;      i += 192) jd[i]  = jump_dest[i];

    const float* xrow = x + (size_t)b * Tn * In;
    if (tid < 64) {
        xb[tid]      = xrow[tid];
        xb[In + tid] = xrow[In + tid];
    }
    __syncthreads();

    if (tid >= 64) {
        const int p = tid - 64;
        float wr[In];
        {
            const float4* w4 = (const float4*)(W_in + p * In);
            #pragma unroll
            for (int i = 0; i < In / 4; ++i) {
                float4 v = w4[i];
                wr[4*i+0] = v.x; wr[4*i+1] = v.y; wr[4*i+2] = v.z; wr[4*i+3] = v.w;
            }
        }
        const float bi = b_in[p];
        {
            float acc = bi;
            #pragma unroll
            for (int i = 0; i < In; ++i) acc += wr[i] * xb[i];
            embb[p] = tanhf(acc);
        }
        __syncthreads();
        for (int t = 0; t < Tn; ++t) {
            if (t + 1 < Tn) {
                const float* xc = xb + ((t + 1) & 1) * In;
                float acc = bi;
                #pragma unroll
                for (int i = 0; i < In; ++i) acc += wr[i] * xc[i];
                embb[((t + 1) & 1) * En + p] = tanhf(acc);
            }
            __syncthreads();
        }
    } else {
        const int l = tid;
        const float lnw0 = ln_w[l],      lnw1 = ln_w[l + 64];
        const float lnb0 = ln_b[l],      lnb1 = ln_b[l + 64];
        const float wg0  = Wg[l],        wg1  = Wg[l + 64];
        const float bgs  = bg[0];
        const float cs   = 1.0f / (1.0f + expf(-cs_ptr[0]));
        float hid0 = 0.0f, hid1 = 0.0f;
        float ptr  = pointer_init[b];
        __syncthreads();

        for (int t = 0; t < Tn; ++t) {
            const bool do_stage = (t + 2 < Tn);
            float xs = 0.0f;
            if (do_stage) xs = xrow[(t + 2) * In + l];

            const float* embc = embb + (t & 1) * En;

            int base = (int)floorf(ptr);
            base = base < 0 ? 0 : (base > Pn - 1 ? Pn - 1 : base);
            int cur = (int)ptr;
            cur = cur < 0 ? 0 : (cur > Pn - 1 ? Pn - 1 : cur);
            const float jt = jd[cur];

            const float frac = ptr - (float)base;
            int   idx[5];
            float wgt[5];
            float mx = -3.4e38f;
            #pragma unroll
            for (int j = 0; j < 5; ++j) {
                idx[j] = (base + j - 2 + Pn) & (Pn - 1);
                float d = (float)(j - 2) - frac;
                float s = -(d * d) * (1.0f / TEMPc);
                wgt[j] = s;
                mx = fmaxf(mx, s);
            }
            float se = 0.0f;
            #pragma unroll
            for (int j = 0; j < 5; ++j) { float ez = expf(wgt[j] - mx); wgt[j] = ez; se += ez; }
            const float inv = 1.0f / se;

            float nb0[5], nb1[5];
            #pragma unroll
            for (int j = 0; j < 5; ++j) {
                nb0[j] = mem[idx[j] * En + l];
                nb1[j] = mem[idx[j] * En + 64 + l];
            }
            float ctx0 = 0.0f, ctx1 = 0.0f;
            #pragma unroll
            for (int j = 0; j < 5; ++j) {
                const float w = wgt[j] * inv; wgt[j] = w;
                ctx0 += w * nb0[j];
                ctx1 += w * nb1[j];
            }

            const float su0 = tanhf(embc[l]      + cs * ctx0 + hid0);
            const float su1 = tanhf(embc[l + 64] + cs * ctx1 + hid1);

            #pragma unroll
            for (int j = 0; j < 5; ++j) {
                mem[idx[j] * En + l]      = nb0[j] + wgt[j] * su0;
                mem[idx[j] * En + 64 + l] = nb1[j] + wgt[j] * su1;
            }

            float s1 = su0 + su1;
            float s2 = su0 * su0 + su1 * su1;
            float s3 = su0 * wg0 + su1 * wg1;
            #pragma unroll
            for (int off = 32; off > 0; off >>= 1) {
                s1 += __shfl_xor(s1, off, 64);
                s2 += __shfl_xor(s2, off, 64);
                s3 += __shfl_xor(s3, off, 64);
            }

            const float mu   = s1 * (1.0f / En);
            const float var  = s2 * (1.0f / En) - mu * mu;
            const float rstd = rsqrtf(var + LN_EPS);
            hid0 = (su0 - mu) * rstd * lnw0 + lnb0;
            hid1 = (su1 - mu) * rstd * lnw1 + lnb1;

            const float jl = s3 + bgs;
            float walk = ptr + 1.0f;
            if (walk >= 256.0f) walk -= 256.0f;
            ptr = (jl > 0.0f) ? jt : walk;

            if (do_stage) xb[(t & 1) * In + l] = xs;
            __syncthreads();
        }
        embb[l]      = hid0;
        embb[l + 64] = hid1;
    }
    __syncthreads();

    if (tid < NOUTn) {
        const float* wrow = Wo + tid * En;
        float acc = bo[tid];
        #pragma unroll 4
        for (int e = 0; e < En; ++e) acc += embb[e] * wrow[e];
        out[b * NOUTn + tid] = acc;
    }
}

extern "C" void kernel_launch(void* const* d_in, const int* in_sizes, int n_in,
                              void* d_out, int out_size, void* d_ws, size_t ws_size,
                              hipStream_t stream) {
    const float* x            = (const float*)d_in[0];
    const float* pointer_init = (const float*)d_in[1];
    const float* W_in         = (const float*)d_in[2];
    const float* b_in         = (const float*)d_in[3];
    const float* ln_w         = (const float*)d_in[4];
    const float* ln_b         = (const float*)d_in[5];
    const float* jump_dest    = (const float*)d_in[6];
    const float* Wg           = (const float*)d_in[7];
    const float* bg           = (const float*)d_in[8];
    const float* cs           = (const float*)d_in[9];
    const float* Wo           = (const float*)d_in[10];
    const float* bo           = (const float*)d_in[11];
    float* out = (float*)d_out;

    const size_t emb_bytes = (size_t)Bn * Tn * En * sizeof(float);   // 128 MiB

    if (ws_size >= emb_bytes) {
        float* emb4 = (float*)d_ws;
        emb4_kernel<<<Bn * 4, 128, 0, stream>>>(x, W_in, b_in, emb4);
        (void)hipFuncSetAttribute((const void*)scan2_kernel,
                                  hipFuncAttributeMaxDynamicSharedMemorySize, LDSG_BYTES);
        scan2_kernel<<<Bn, 64, LDSG_BYTES, stream>>>(
            emb4, pointer_init, ln_w, ln_b, jump_dest, Wg, bg, cs, Wo, bo, out);
    } else {
        (void)hipFuncSetAttribute((const void*)ring_kernel,
                                  hipFuncAttributeMaxDynamicSharedMemorySize, LDS_BYTES);
        ring_kernel<<<Bn, 192, LDS_BYTES, stream>>>(
            x, pointer_init, W_in, b_in, ln_w, ln_b, jump_dest, Wg, bg, cs, Wo, bo, out);
    }
}

// Round 4
// 630.489 us; speedup vs baseline: 1.5699x; 1.2339x over previous
//
#include <hip/hip_runtime.h>
#include <math.h>

// Problem constants (from reference)
#define Bn    256
#define Tn    1024
#define In    64
#define Pn    256
#define En    128
#define NOUTn 64
#define LN_EPS 1e-5f

// softmax factorization constants (TEMP=8):
// z_j ∝ exp((j-2)*frac/4) * exp(-(j-2)^2/8)  (common exp(-frac^2/8) cancels)
#define C1f 0.3606737602222409f     // log2(e)/4
#define K1f 0.8824969025845955f     // exp(-1/8)
#define K2f 0.6065306597126334f     // exp(-4/8)

__device__ __forceinline__ float tanh_fast(float x) {
    float e = __builtin_amdgcn_exp2f(x * 2.88539008177793f);   // e^(2x)
    return 1.0f - 2.0f * __builtin_amdgcn_rcpf(e + 1.0f);
}

template<int CTRL, int RMASK>
__device__ __forceinline__ float dpp_add(float x) {
    return x + __int_as_float(__builtin_amdgcn_update_dpp(
        0, __float_as_int(x), CTRL, RMASK, 0xF, false));
}
__device__ __forceinline__ void wave_sum64_x3(float& x, float& y, float& z) {
#define LVL(C, R) x = dpp_add<C, R>(x); y = dpp_add<C, R>(y); z = dpp_add<C, R>(z);
    LVL(0x111, 0xF)
    LVL(0x112, 0xF)
    LVL(0x114, 0xF)
    LVL(0x118, 0xF)
    LVL(0x142, 0xA)
    LVL(0x143, 0xC)
#undef LVL
    x = __int_as_float(__builtin_amdgcn_readlane(__float_as_int(x), 63));
    y = __int_as_float(__builtin_amdgcn_readlane(__float_as_int(y), 63));
    z = __int_as_float(__builtin_amdgcn_readlane(__float_as_int(z), 63));
}

// ===========================================================================
// Pass A: emb4[b][t/4][e][t%4] = tanh(x . W_in[e] + b_in[e])
// Register-tiled GEMM: thread = 8 consecutive t x 8 strided e.
// W in LDS (row stride 68 floats -> 16B-aligned b128 reads, conflict-free);
// x via per-lane VMEM dwordx4 (deep vmcnt MLP -- the R3 SMEM serialization fix).
// Grid: Bn*8 blocks x 256 threads; block covers 128 t x 128 e.
// ===========================================================================
__global__ __launch_bounds__(256)
void embgemm_kernel(const float* __restrict__ x, const float* __restrict__ W_in,
                    const float* __restrict__ b_in, float* __restrict__ emb4) {
    __shared__ float wlds[128 * 68];            // 34 KB, padded rows
    const int tid = threadIdx.x;
    for (int i = tid; i < 128 * 64; i += 256)
        wlds[(i >> 6) * 68 + (i & 63)] = W_in[i];
    __syncthreads();

    const int b    = blockIdx.x >> 3;
    const int tseg = blockIdx.x & 7;            // which 128-t segment
    const int w    = tid >> 6;
    const int l    = tid & 63;
    const int t0   = tseg * 128 + (w >> 1) * 64 + (l >> 3) * 8;  // 8 consecutive t
    const int e0   = (w & 1) * 64 + (l & 7);    // e = e0 + 8*j (lane-contiguous stores)

    float acc[8][8];
    #pragma unroll
    for (int i = 0; i < 8; ++i)
        #pragma unroll
        for (int j = 0; j < 8; ++j) acc[i][j] = 0.f;

    const float4* xrow = (const float4*)(x + ((size_t)b * Tn + t0) * In);

    for (int i4 = 0; i4 < 16; ++i4) {
        float4 xv[8];
        #pragma unroll
        for (int tt = 0; tt < 8; ++tt) xv[tt] = xrow[tt * 16 + i4];
        float4 wf[8];
        #pragma unroll
        for (int j = 0; j < 8; ++j)
            wf[j] = *(const float4*)&wlds[(e0 + 8 * j) * 68 + i4 * 4];
        #pragma unroll
        for (int tt = 0; tt < 8; ++tt)
            #pragma unroll
            for (int j = 0; j < 8; ++j) {
                acc[tt][j] += xv[tt].x * wf[j].x;
                acc[tt][j] += xv[tt].y * wf[j].y;
                acc[tt][j] += xv[tt].z * wf[j].z;
                acc[tt][j] += xv[tt].w * wf[j].w;
            }
    }

    const int tb0 = t0 >> 2;
    #pragma unroll
    for (int j = 0; j < 8; ++j) {
        const int e = e0 + 8 * j;
        const float be = b_in[e];
        #pragma unroll
        for (int tb = 0; tb < 2; ++tb) {
            float4 o;
            o.x = tanh_fast(acc[tb * 4 + 0][j] + be);
            o.y = tanh_fast(acc[tb * 4 + 1][j] + be);
            o.z = tanh_fast(acc[tb * 4 + 2][j] + be);
            o.w = tanh_fast(acc[tb * 4 + 3][j] + be);
            *(float4*)&emb4[(((size_t)b * 256 + tb0 + tb) * 128 + e) * 4] = o;
        }
    }
}

// ===========================================================================
// Pass B: speculative dual-path scan. ONE WAVE per batch, no barriers.
// Both next-pointer candidates (walk / jump) are prepared during step t:
//   walk path: same weights (frac unchanged), values = current scatter regs
//              + one fresh LDS row; jump path: 5 LDS read2 issued right after
//              the scatter. Gate select = cndmask -> gather latency off-chain.
// ===========================================================================
#define LDSG_FLOATS (Pn * En + Pn)
#define LDSG_BYTES  (LDSG_FLOATS * 4)

__global__ __launch_bounds__(64, 1)
void scan3_kernel(const float* __restrict__ emb4,
                  const float* __restrict__ pointer_init,
                  const float* __restrict__ ln_w, const float* __restrict__ ln_b,
                  const float* __restrict__ jump_dest,
                  const float* __restrict__ Wg,  const float* __restrict__ bg,
                  const float* __restrict__ cs_ptr,
                  const float* __restrict__ Wo,  const float* __restrict__ bo,
                  float* __restrict__ out) {
    extern __shared__ float lds[];
    float* mem = lds;              // Pn*En ring memory, column e owned by lane
    float* jd  = lds + Pn * En;    // jump_dest copy

    const int b = blockIdx.x;
    const int l = threadIdx.x;

    float4* m4 = (float4*)mem;
    for (int i = l; i < Pn * En / 4; i += 64) m4[i] = make_float4(0.f, 0.f, 0.f, 0.f);
    for (int i = l; i < Pn; i += 64) jd[i] = jump_dest[i];

    const float lnw0 = ln_w[l], lnw1 = ln_w[l + 64];
    const float lnb0 = ln_b[l], lnb1 = ln_b[l + 64];
    const float wg0  = Wg[l],   wg1  = Wg[l + 64];
    const float bgs  = bg[0];
    const float cs   = 1.0f / (1.0f + expf(-cs_ptr[0]));
    float hid0 = 0.f, hid1 = 0.f;

    const float4* e40 = (const float4*)(emb4 + ((size_t)b << 17)) + l;   // ch l
    const float4* e41 = e40 + 64;                                        // ch l+64
    float4 A0 = e40[0],   A1 = e41[0];
    float4 B0 = e40[128], B1 = e41[128];

    // ---------------- mutable pipeline state ----------------
    float jl;                                    // gate value from step t-1
    int   baseW, baseJ;                          // candidate bases for ptr(t)
    float ptrW, jtc;                             // walk candidate value; jump candidate value
    float invW, invJ;
    float zW0, zW1, zW2, zW3, zW4, zJ0, zJ1, zJ2, zJ3, zJ4;
    float W00, W01, W02, W03, W04, W10, W11, W12, W13, W14;  // walk nb values
    float J00, J01, J02, J03, J04, J10, J11, J12, J13, J14;  // jump nb values (LDS)
    float jtW_rd, jtJ_rd;                        // jd[baseW], jd[baseJ]

    // ---------------- prologue: plain step 0 ----------------
    {
        const float ptr = pointer_init[b];
        int base = (int)ptr; base = base < 0 ? 0 : (base > 255 ? 255 : base);
        const float frac = ptr - (float)base;
        const float r  = __builtin_amdgcn_exp2f(frac * C1f);
        const float ri = __builtin_amdgcn_exp2f(-frac * C1f);
        const float z0 = K2f * ri * ri, z1 = K1f * ri, z2 = 1.0f,
                    z3 = K1f * r,       z4 = K2f * r * r;
        const float inv = __builtin_amdgcn_rcpf(((z0 + z1) + (z2 + z3)) + z4);

        float* r0 = mem + (((base + 254) & 255) << 7) + l;
        float* r1 = mem + (((base + 255) & 255) << 7) + l;
        float* r2 = mem + (base << 7) + l;
        float* r3 = mem + (((base + 1) & 255) << 7) + l;
        float* r4 = mem + (((base + 2) & 255) << 7) + l;
        const float n00 = r0[0],  n01 = r1[0],  n02 = r2[0],  n03 = r3[0],  n04 = r4[0];
        const float n10 = r0[64], n11 = r1[64], n12 = r2[64], n13 = r3[64], n14 = r4[64];

        const float ctx0 = inv * (((z0*n00 + z1*n01) + (z2*n02 + z3*n03)) + z4*n04);
        const float ctx1 = inv * (((z0*n10 + z1*n11) + (z2*n12 + z3*n13)) + z4*n14);
        const float su0 = tanh_fast(A0.x + cs * ctx0);
        const float su1 = tanh_fast(A1.x + cs * ctx1);
        const float g0 = inv * su0, g1 = inv * su1;
        const float m00 = n00 + z0*g0, m01 = n01 + z1*g0, m02 = n02 + z2*g0,
                    m03 = n03 + z3*g0, m04 = n04 + z4*g0;
        const float m10 = n10 + z0*g1, m11 = n11 + z1*g1, m12 = n12 + z2*g1,
                    m13 = n13 + z3*g1, m14 = n14 + z4*g1;
        r0[0] = m00; r0[64] = m10; r1[0] = m01; r1[64] = m11;
        r2[0] = m02; r2[64] = m12; r3[0] = m03; r3[64] = m13;
        r4[0] = m04; r4[64] = m14;

        // candidates for step 1
        baseW = (base + 1) & 255;
        ptrW  = ptr + 1.0f; if (ptrW >= 256.0f) ptrW -= 256.0f;
        jtc   = jd[base];
        int bj = (int)jtc; bj = bj < 0 ? 0 : (bj > 255 ? 255 : bj);
        baseJ = bj;
        const float fracJ = jtc - (float)bj;
        const float rj  = __builtin_amdgcn_exp2f(fracJ * C1f);
        const float rji = __builtin_amdgcn_exp2f(-fracJ * C1f);
        zJ0 = K2f * rji * rji; zJ1 = K1f * rji; zJ2 = 1.0f;
        zJ3 = K1f * rj;        zJ4 = K2f * rj * rj;
        invJ = __builtin_amdgcn_rcpf(((zJ0 + zJ1) + (zJ2 + zJ3)) + zJ4);

        const float* q0 = mem + (((bj + 254) & 255) << 7) + l;
        const float* q1 = mem + (((bj + 255) & 255) << 7) + l;
        const float* q2 = mem + (bj << 7) + l;
        const float* q3 = mem + (((bj + 1) & 255) << 7) + l;
        const float* q4 = mem + (((bj + 2) & 255) << 7) + l;
        J00 = q0[0];  J01 = q1[0];  J02 = q2[0];  J03 = q3[0];  J04 = q4[0];
        J10 = q0[64]; J11 = q1[64]; J12 = q2[64]; J13 = q3[64]; J14 = q4[64];

        const float* qe = mem + (((base + 3) & 255) << 7) + l;
        W00 = m01; W01 = m02; W02 = m03; W03 = m04; W04 = qe[0];
        W10 = m11; W11 = m12; W12 = m13; W13 = m14; W14 = qe[64];
        zW0 = z0; zW1 = z1; zW2 = z2; zW3 = z3; zW4 = z4; invW = inv;
        jtW_rd = jd[baseW]; jtJ_rd = jd[baseJ];

        float s1 = su0 + su1;
        float s2 = su0 * su0 + su1 * su1;
        float s3 = su0 * wg0 + su1 * wg1;
        wave_sum64_x3(s1, s2, s3);
        const float mu   = s1 * (1.0f / En);
        const float var  = s2 * (1.0f / En) - mu * mu;
        const float rstd = __builtin_amdgcn_rsqf(var + LN_EPS);
        hid0 = (su0 - mu) * rstd * lnw0 + lnb0;
        hid1 = (su1 - mu) * rstd * lnw1 + lnb1;
        jl = s3 + bgs;
    }

#define SSTEP(EC0, EC1) {                                                      \
    const bool sel = jl > 0.0f;                                                \
    const int   base = sel ? baseJ : baseW;                                    \
    const float inv  = sel ? invJ : invW;                                      \
    const float z0 = sel ? zJ0 : zW0, z1 = sel ? zJ1 : zW1,                    \
                z2 = sel ? zJ2 : zW2, z3 = sel ? zJ3 : zW3,                    \
                z4 = sel ? zJ4 : zW4;                                          \
    const float ptrn  = sel ? jtc : ptrW;                                      \
    const float jtc_n = sel ? jtJ_rd : jtW_rd;                                 \
    const float n00 = sel ? J00 : W00, n01 = sel ? J01 : W01,                  \
                n02 = sel ? J02 : W02, n03 = sel ? J03 : W03,                  \
                n04 = sel ? J04 : W04;                                         \
    const float n10 = sel ? J10 : W10, n11 = sel ? J11 : W11,                  \
                n12 = sel ? J12 : W12, n13 = sel ? J13 : W13,                  \
                n14 = sel ? J14 : W14;                                         \
    const float ctx0 = inv * (((z0*n00 + z1*n01) + (z2*n02 + z3*n03)) + z4*n04); \
    const float ctx1 = inv * (((z0*n10 + z1*n11) + (z2*n12 + z3*n13)) + z4*n14); \
    const float su0 = tanh_fast((EC0) + cs * ctx0 + hid0);                     \
    const float su1 = tanh_fast((EC1) + cs * ctx1 + hid1);                     \
    const float g0 = inv * su0, g1 = inv * su1;                                \
    const float m01v = n01 + z1*g0, m02v = n02 + z2*g0,                        \
                m03v = n03 + z3*g0, m04v = n04 + z4*g0;                        \
    const float m11v = n11 + z1*g1, m12v = n12 + z2*g1,                        \
                m13v = n13 + z3*g1, m14v = n14 + z4*g1;                        \
    float* r0 = mem + (((base + 254) & 255) << 7) + l;                         \
    float* r1 = mem + (((base + 255) & 255) << 7) + l;                         \
    float* r2 = mem + (base << 7) + l;                                         \
    float* r3 = mem + (((base + 1) & 255) << 7) + l;                           \
    float* r4 = mem + (((base + 2) & 255) << 7) + l;                           \
    r0[0] = n00 + z0*g0; r0[64] = n10 + z0*g1;                                 \
    r1[0] = m01v; r1[64] = m11v; r2[0] = m02v; r2[64] = m12v;                  \
    r3[0] = m03v; r3[64] = m13v; r4[0] = m04v; r4[64] = m14v;                  \
    /* next candidates: issue all LDS reads ASAP (post-scatter order) */       \
    jtc = jtc_n;                                                               \
    int bj = (int)jtc; bj = bj < 0 ? 0 : (bj > 255 ? 255 : bj);                \
    baseJ = bj;                                                                \
    const float fracJ = jtc - (float)bj;                                       \
    const float* q0 = mem + (((bj + 254) & 255) << 7) + l;                     \
    const float* q1 = mem + (((bj + 255) & 255) << 7) + l;                     \
    const float* q2 = mem + (bj << 7) + l;                                     \
    const float* q3 = mem + (((bj + 1) & 255) << 7) + l;                       \
    const float* q4 = mem + (((bj + 2) & 255) << 7) + l;                       \
    J00 = q0[0];  J01 = q1[0];  J02 = q2[0];  J03 = q3[0];  J04 = q4[0];       \
    J10 = q0[64]; J11 = q1[64]; J12 = q2[64]; J13 = q3[64]; J14 = q4[64];      \
    const float* qe = mem + (((base + 3) & 255) << 7) + l;                     \
    W00 = m01v; W01 = m02v; W02 = m03v; W03 = m04v; W04 = qe[0];               \
    W10 = m11v; W11 = m12v; W12 = m13v; W13 = m14v; W14 = qe[64];              \
    baseW = (base + 1) & 255;                                                  \
    ptrW  = ptrn + 1.0f; if (ptrW >= 256.0f) ptrW -= 256.0f;                   \
    jtW_rd = jd[baseW]; jtJ_rd = jd[baseJ];                                    \
    zW0 = z0; zW1 = z1; zW2 = z2; zW3 = z3; zW4 = z4; invW = inv;              \
    const float rj  = __builtin_amdgcn_exp2f(fracJ * C1f);                     \
    const float rji = __builtin_amdgcn_exp2f(-fracJ * C1f);                    \
    zJ0 = K2f * rji * rji; zJ1 = K1f * rji; zJ2 = 1.0f;                        \
    zJ3 = K1f * rj;        zJ4 = K2f * rj * rj;                                \
    invJ = __builtin_amdgcn_rcpf(((zJ0 + zJ1) + (zJ2 + zJ3)) + zJ4);           \
    float s1 = su0 + su1;                                                      \
    float s2 = su0 * su0 + su1 * su1;                                          \
    float s3 = su0 * wg0 + su1 * wg1;                                          \
    wave_sum64_x3(s1, s2, s3);                                                 \
    const float mu   = s1 * (1.0f / En);                                       \
    const float var  = s2 * (1.0f / En) - mu * mu;                             \
    const float rstd = __builtin_amdgcn_rsqf(var + LN_EPS);                    \
    hid0 = (su0 - mu) * rstd * lnw0 + lnb0;                                    \
    hid1 = (su1 - mu) * rstd * lnw1 + lnb1;                                    \
    jl = s3 + bgs;                                                             \
}

    // tb = 0 (step 0 consumed by prologue)
    {
        float4 C0 = e40[2 << 7], C1 = e41[2 << 7];
        SSTEP(A0.y, A1.y)
        SSTEP(A0.z, A1.z)
        SSTEP(A0.w, A1.w)
        A0 = B0; A1 = B1; B0 = C0; B1 = C1;
    }
    for (int tb = 1; tb < 256; ++tb) {
        const int tp = tb + 2 > 255 ? 255 : tb + 2;
        float4 C0 = e40[tp << 7];
        float4 C1 = e41[tp << 7];
        SSTEP(A0.x, A1.x)
        SSTEP(A0.y, A1.y)
        SSTEP(A0.z, A1.z)
        SSTEP(A0.w, A1.w)
        A0 = B0; A1 = B1; B0 = C0; B1 = C1;
    }
#undef SSTEP

    // epilogue: logits = hid @ Wo^T + bo
    mem[l] = hid0; mem[64 + l] = hid1;
    __syncthreads();
    const float4* w4 = (const float4*)(Wo + l * En);
    const float4* h4 = (const float4*)mem;
    float a0 = 0.f, a1 = 0.f, a2 = 0.f, a3 = 0.f;
    #pragma unroll
    for (int i = 0; i < En / 4; ++i) {
        float4 wv = w4[i]; float4 hv = h4[i];
        a0 += wv.x * hv.x; a1 += wv.y * hv.y; a2 += wv.z * hv.z; a3 += wv.w * hv.w;
    }
    out[b * NOUTn + l] = (a0 + a1) + (a2 + a3) + bo[l];
}

// ===========================================================================
// Fallback (ws too small for the 128 MiB emb buffer): round-1 kernel.
// ===========================================================================
#define LDS_FLOATS (Pn*En + 2*En + 2*In + Pn)
#define LDS_BYTES  (LDS_FLOATS * 4)

__global__ __launch_bounds__(192, 1)
void ring_kernel(const float* __restrict__ x,
                 const float* __restrict__ pointer_init,
                 const float* __restrict__ W_in,
                 const float* __restrict__ b_in,
                 const float* __restrict__ ln_w,
                 const float* __restrict__ ln_b,
                 const float* __restrict__ jump_dest,
                 const float* __restrict__ Wg,
                 const float* __restrict__ bg,
                 const float* __restrict__ cs_ptr,
                 const float* __restrict__ Wo,
                 const float* __restrict__ bo,
                 float* __restrict__ out)
{
    extern __shared__ float lds[];
    float* mem  = lds;
    float* embb = mem + Pn * En;
    float* xb   = embb + 2 * En;
    float* jd   = xb + 2 * In;

    const int b   = blockIdx.x;
    const int tid = threadIdx.x;

    for (int i = tid; i < Pn * En; i += 192) mem[i] = 0.0f;
    for (int i = tid; i < Pn;      i += 192) jd[i]  = jump_dest[i];

    const float* xrow = x + (size_t)b * Tn * In;
    if (tid < 64) {
        xb[tid]      = xrow[tid];
        xb[In + tid] = xrow[In + tid];
    }
    __syncthreads();

    if (tid >= 64) {
        const int p = tid - 64;
        float wr[In];
        {
            const float4* w4 = (const float4*)(W_in + p * In);
            #pragma unroll
            for (int i = 0; i < In / 4; ++i) {
                float4 v = w4[i];
                wr[4*i+0] = v.x; wr[4*i+1] = v.y; wr[4*i+2] = v.z; wr[4*i+3] = v.w;
            }
        }
        const float bi = b_in[p];
        {
            float acc = bi;
            #pragma unroll
            for (int i = 0; i < In; ++i) acc += wr[i] * xb[i];
            embb[p] = tanhf(acc);
        }
        __syncthreads();
        for (int t = 0; t < Tn; ++t) {
            if (t + 1 < Tn) {
                const float* xc = xb + ((t + 1) & 1) * In;
                float acc = bi;
                #pragma unroll
                for (int i = 0; i < In; ++i) acc += wr[i] * xc[i];
                embb[((t + 1) & 1) * En + p] = tanhf(acc);
            }
            __syncthreads();
        }
    } else {
        const int l = tid;
        const float lnw0 = ln_w[l],      lnw1 = ln_w[l + 64];
        const float lnb0 = ln_b[l],      lnb1 = ln_b[l + 64];
        const float wg0  = Wg[l],        wg1  = Wg[l + 64];
        const float bgs  = bg[0];
        const float cs   = 1.0f / (1.0f + expf(-cs_ptr[0]));
        float hid0 = 0.0f, hid1 = 0.0f;
        float ptr  = pointer_init[b];
        __syncthreads();

        for (int t = 0; t < Tn; ++t) {
            const bool do_stage = (t + 2 < Tn);
            float xs = 0.0f;
            if (do_stage) xs = xrow[(t + 2) * In + l];

            const float* embc = embb + (t & 1) * En;

            int base = (int)floorf(ptr);
            base = base < 0 ? 0 : (base > Pn - 1 ? Pn - 1 : base);
            int cur = (int)ptr;
            cur = cur < 0 ? 0 : (cur > Pn - 1 ? Pn - 1 : cur);
            const float jt = jd[cur];

            const float frac = ptr - (float)base;
            int   idx[5];
            float wgt[5];
            float mx = -3.4e38f;
            #pragma unroll
            for (int j = 0; j < 5; ++j) {
                idx[j] = (base + j - 2 + Pn) & (Pn - 1);
                float d = (float)(j - 2) - frac;
                float s = -(d * d) * 0.125f;
                wgt[j] = s;
                mx = fmaxf(mx, s);
            }
            float se = 0.0f;
            #pragma unroll
            for (int j = 0; j < 5; ++j) { float ez = expf(wgt[j] - mx); wgt[j] = ez; se += ez; }
            const float inv = 1.0f / se;

            float nb0[5], nb1[5];
            #pragma unroll
            for (int j = 0; j < 5; ++j) {
                nb0[j] = mem[idx[j] * En + l];
                nb1[j] = mem[idx[j] * En + 64 + l];
            }
            float ctx0 = 0.0f, ctx1 = 0.0f;
            #pragma unroll
            for (int j = 0; j < 5; ++j) {
                const float w = wgt[j] * inv; wgt[j] = w;
                ctx0 += w * nb0[j];
                ctx1 += w * nb1[j];
            }

            const float su0 = tanhf(embc[l]      + cs * ctx0 + hid0);
            const float su1 = tanhf(embc[l + 64] + cs * ctx1 + hid1);

            #pragma unroll
            for (int j = 0; j < 5; ++j) {
                mem[idx[j] * En + l]      = nb0[j] + wgt[j] * su0;
                mem[idx[j] * En + 64 + l] = nb1[j] + wgt[j] * su1;
            }

            float s1 = su0 + su1;
            float s2 = su0 * su0 + su1 * su1;
            float s3 = su0 * wg0 + su1 * wg1;
            #pragma unroll
            for (int off = 32; off > 0; off >>= 1) {
                s1 += __shfl_xor(s1, off, 64);
                s2 += __shfl_xor(s2, off, 64);
                s3 += __shfl_xor(s3, off, 64);
            }

            const float mu   = s1 * (1.0f / En);
            const float var  = s2 * (1.0f / En) - mu * mu;
            const float rstd = rsqrtf(var + LN_EPS);
            hid0 = (su0 - mu) * rstd * lnw0 + lnb0;
            hid1 = (su1 - mu) * rstd * lnw1 + lnb1;

            const float jl = s3 + bgs;
            float walk = ptr + 1.0f;
            if (walk >= 256.0f) walk -= 256.0f;
            ptr = (jl > 0.0f) ? jt : walk;

            if (do_stage) xb[(t & 1) * In + l] = xs;
            __syncthreads();
        }
        embb[l]      = hid0;
        embb[l + 64] = hid1;
    }
    __syncthreads();

    if (tid < NOUTn) {
        const float* wrow = Wo + tid * En;
        float acc = bo[tid];
        #pragma unroll 4
        for (int e = 0; e < En; ++e) acc += embb[e] * wrow[e];
        out[b * NOUTn + tid] = acc;
    }
}

extern "C" void kernel_launch(void* const* d_in, const int* in_sizes, int n_in,
                              void* d_out, int out_size, void* d_ws, size_t ws_size,
                              hipStream_t stream) {
    const float* x            = (const float*)d_in[0];
    const float* pointer_init = (const float*)d_in[1];
    const float* W_in         = (const float*)d_in[2];
    const float* b_in         = (const float*)d_in[3];
    const float* ln_w         = (const float*)d_in[4];
    const float* ln_b         = (const float*)d_in[5];
    const float* jump_dest    = (const float*)d_in[6];
    const float* Wg           = (const float*)d_in[7];
    const float* bg           = (const float*)d_in[8];
    const float* cs           = (const float*)d_in[9];
    const float* Wo           = (const float*)d_in[10];
    const float* bo           = (const float*)d_in[11];
    float* out = (float*)d_out;

    const size_t emb_bytes = (size_t)Bn * Tn * En * sizeof(float);   // 128 MiB

    if (ws_size >= emb_bytes) {
        float* emb4 = (float*)d_ws;
        embgemm_kernel<<<Bn * 8, 256, 0, stream>>>(x, W_in, b_in, emb4);
        (void)hipFuncSetAttribute((const void*)scan3_kernel,
                                  hipFuncAttributeMaxDynamicSharedMemorySize, LDSG_BYTES);
        scan3_kernel<<<Bn, 64, LDSG_BYTES, stream>>>(
            emb4, pointer_init, ln_w, ln_b, jump_dest, Wg, bg, cs, Wo, bo, out);
    } else {
        (void)hipFuncSetAttribute((const void*)ring_kernel,
                                  hipFuncAttributeMaxDynamicSharedMemorySize, LDS_BYTES);
        ring_kernel<<<Bn, 192, LDS_BYTES, stream>>>(
            x, pointer_init, W_in, b_in, ln_w, ln_b, jump_dest, Wg, bg, cs, Wo, bo, out);
    }
}

// Round 5
// 519.600 us; speedup vs baseline: 1.9050x; 1.2134x over previous
//
#include <hip/hip_runtime.h>
#include <math.h>

// Problem constants (from reference)
#define Bn    256
#define Tn    1024
#define In    64
#define Pn    256
#define En    128
#define NOUTn 64
#define LN_EPS 1e-5f

// softmax factorization constants (TEMP=8):
// z_j ∝ exp((j-2)*frac/4) * exp(-(j-2)^2/8)  (common exp(-frac^2/8) cancels)
#define C1f 0.3606737602222409f     // log2(e)/4
#define K1f 0.8824969025845955f     // exp(-1/8)
#define K2f 0.6065306597126334f     // exp(-4/8)

typedef float f32x2 __attribute__((ext_vector_type(2)));

__device__ __forceinline__ float tanh_fast(float x) {
    float e = __builtin_amdgcn_exp2f(x * 2.88539008177793f);   // e^(2x)
    return 1.0f - 2.0f * __builtin_amdgcn_rcpf(e + 1.0f);
}
__device__ __forceinline__ f32x2 tanh2(f32x2 x) {
    f32x2 e;
    e[0] = __builtin_amdgcn_exp2f(x[0] * 2.88539008177793f);
    e[1] = __builtin_amdgcn_exp2f(x[1] * 2.88539008177793f);
    f32x2 r;
    r[0] = __builtin_amdgcn_rcpf(e[0] + 1.0f);
    r[1] = __builtin_amdgcn_rcpf(e[1] + 1.0f);
    return 1.0f - 2.0f * r;
}

template<int CTRL, int RMASK>
__device__ __forceinline__ float dpp_add(float x) {
    return x + __int_as_float(__builtin_amdgcn_update_dpp(
        0, __float_as_int(x), CTRL, RMASK, 0xF, false));
}
__device__ __forceinline__ void wave_sum64_x3(float& x, float& y, float& z) {
#define LVL(C, R) x = dpp_add<C, R>(x); y = dpp_add<C, R>(y); z = dpp_add<C, R>(z);
    LVL(0x111, 0xF)
    LVL(0x112, 0xF)
    LVL(0x114, 0xF)
    LVL(0x118, 0xF)
    LVL(0x142, 0xA)
    LVL(0x143, 0xC)
#undef LVL
    x = __int_as_float(__builtin_amdgcn_readlane(__float_as_int(x), 63));
    y = __int_as_float(__builtin_amdgcn_readlane(__float_as_int(y), 63));
    z = __int_as_float(__builtin_amdgcn_readlane(__float_as_int(z), 63));
}

// ===========================================================================
// Pass A: emb4[b][t/4][e][t%4] = tanh(x . W_in[e] + b_in[e])
// Register-tiled GEMM (unchanged from R4: ~72 us, VMEM-MLP-bound).
// ===========================================================================
__global__ __launch_bounds__(256)
void embgemm_kernel(const float* __restrict__ x, const float* __restrict__ W_in,
                    const float* __restrict__ b_in, float* __restrict__ emb4) {
    __shared__ float wlds[128 * 68];
    const int tid = threadIdx.x;
    for (int i = tid; i < 128 * 64; i += 256)
        wlds[(i >> 6) * 68 + (i & 63)] = W_in[i];
    __syncthreads();

    const int b    = blockIdx.x >> 3;
    const int tseg = blockIdx.x & 7;
    const int w    = tid >> 6;
    const int l    = tid & 63;
    const int t0   = tseg * 128 + (w >> 1) * 64 + (l >> 3) * 8;
    const int e0   = (w & 1) * 64 + (l & 7);

    float acc[8][8];
    #pragma unroll
    for (int i = 0; i < 8; ++i)
        #pragma unroll
        for (int j = 0; j < 8; ++j) acc[i][j] = 0.f;

    const float4* xrow = (const float4*)(x + ((size_t)b * Tn + t0) * In);

    for (int i4 = 0; i4 < 16; ++i4) {
        float4 xv[8];
        #pragma unroll
        for (int tt = 0; tt < 8; ++tt) xv[tt] = xrow[tt * 16 + i4];
        float4 wf[8];
        #pragma unroll
        for (int j = 0; j < 8; ++j)
            wf[j] = *(const float4*)&wlds[(e0 + 8 * j) * 68 + i4 * 4];
        #pragma unroll
        for (int tt = 0; tt < 8; ++tt)
            #pragma unroll
            for (int j = 0; j < 8; ++j) {
                acc[tt][j] += xv[tt].x * wf[j].x;
                acc[tt][j] += xv[tt].y * wf[j].y;
                acc[tt][j] += xv[tt].z * wf[j].z;
                acc[tt][j] += xv[tt].w * wf[j].w;
            }
    }

    const int tb0 = t0 >> 2;
    #pragma unroll
    for (int j = 0; j < 8; ++j) {
        const int e = e0 + 8 * j;
        const float be = b_in[e];
        #pragma unroll
        for (int tb = 0; tb < 2; ++tb) {
            float4 o;
            o.x = tanh_fast(acc[tb * 4 + 0][j] + be);
            o.y = tanh_fast(acc[tb * 4 + 1][j] + be);
            o.z = tanh_fast(acc[tb * 4 + 2][j] + be);
            o.w = tanh_fast(acc[tb * 4 + 3][j] + be);
            *(float4*)&emb4[(((size_t)b * 256 + tb0 + tb) * 128 + e) * 4] = o;
        }
    }
}

// ===========================================================================
// Pass B: scan, ONE WAVE per batch. Ring layout interleaved: mem[row*128+2l+c]
// holds channels (l, l+64) adjacent -> one ds_read_b64/ds_write_b64 per row.
// Packed f32 (v_pk_fma) for all channel-pair math. Wave-uniform scalar branch:
//   walk step: weights unchanged, window = scattered regs + 1 prefetched row
//              (zero gather latency, zero exp2)
//   jump step: full gather + weight recompute (pays LDS latency)
// Prologue folded into the loop by forcing jl=+1, jt_cur=pointer_init.
// ===========================================================================
#define LDSG_FLOATS (Pn * En + Pn)
#define LDSG_BYTES  (LDSG_FLOATS * 4)

__global__ __launch_bounds__(64, 1)
void scan4_kernel(const float* __restrict__ emb4,
                  const float* __restrict__ pointer_init,
                  const float* __restrict__ ln_w, const float* __restrict__ ln_b,
                  const float* __restrict__ jump_dest,
                  const float* __restrict__ Wg,  const float* __restrict__ bg,
                  const float* __restrict__ cs_ptr,
                  const float* __restrict__ Wo,  const float* __restrict__ bo,
                  float* __restrict__ out) {
    extern __shared__ float lds[];
    float* mem = lds;              // ring: [row][2*l + c]
    float* jd  = lds + Pn * En;    // jump_dest copy

    const int b = blockIdx.x;
    const int l = threadIdx.x;

    float4* m4 = (float4*)mem;
    for (int i = l; i < Pn * En / 4; i += 64) m4[i] = make_float4(0.f, 0.f, 0.f, 0.f);
    for (int i = l; i < Pn; i += 64) jd[i] = jump_dest[i];
    // single wave: DS program order suffices, no barrier needed

    const f32x2 lnw = {ln_w[l], ln_w[l + 64]};
    const f32x2 lnb = {ln_b[l], ln_b[l + 64]};
    const f32x2 wg  = {Wg[l],   Wg[l + 64]};
    const float bgs = bg[0];
    const float cs  = 1.0f / (1.0f + expf(-cs_ptr[0]));
    f32x2 hid = {0.f, 0.f};

    float* myb = mem + 2 * l;      // lane's channel-pair base

    const float4* e40 = (const float4*)(emb4 + ((size_t)b << 17)) + l;   // ch l
    const float4* e41 = e40 + 64;                                        // ch l+64
    float4 A0 = e40[0],   A1 = e41[0];
    float4 B0 = e40[128], B1 = e41[128];

    // ---- pipeline state (entry invariant before step t) ----
    float jl     = 1.0f;              // force jump at t=0
    float jt_cur = pointer_init[b];   // "jump target" = initial pointer
    float ptrW   = 0.f;
    int   baseW  = 0;
    float jtW_pre = 0.f;
    float z0 = 0.f, z1 = 0.f, z2 = 1.f, z3 = 0.f, z4 = 0.f, inv = 1.f;
    f32x2 wnb0 = {0,0}, wnb1 = {0,0}, wnb2 = {0,0}, wnb3 = {0,0}, wnb4 = {0,0};
    float *wp0 = myb, *wp1 = myb, *wp2 = myb, *wp3 = myb, *wp4 = myb;

#define SSTEP(EC0, EC1) {                                                      \
    float ptr; int base;                                                       \
    f32x2 nb0, nb1, nb2, nb3, nb4;                                             \
    float *p0, *p1, *p2, *p3, *p4;                                             \
    float jt_nxt;                                                              \
    if (__builtin_amdgcn_readfirstlane(__float_as_int(jl)) > 0) {              \
        /* JUMP: full gather + weight recompute */                             \
        ptr  = jt_cur;                                                         \
        base = (int)ptr; base = base > 255 ? 255 : base;                       \
        p0 = mem + (((base + 254) & 255) << 7) + 2 * l;                        \
        p1 = mem + (((base + 255) & 255) << 7) + 2 * l;                        \
        p2 = mem + (base << 7) + 2 * l;                                        \
        p3 = mem + (((base + 1) & 255) << 7) + 2 * l;                          \
        p4 = mem + (((base + 2) & 255) << 7) + 2 * l;                          \
        nb0 = *(f32x2*)p0; nb1 = *(f32x2*)p1; nb2 = *(f32x2*)p2;               \
        nb3 = *(f32x2*)p3; nb4 = *(f32x2*)p4;                                  \
        jt_nxt = jd[base];                                                     \
        const float frac = ptr - (float)base;                                  \
        const float r  = __builtin_amdgcn_exp2f(frac * C1f);                   \
        const float ri = __builtin_amdgcn_exp2f(-frac * C1f);                  \
        z0 = K2f * ri * ri; z1 = K1f * ri; z2 = 1.0f;                          \
        z3 = K1f * r;       z4 = K2f * r * r;                                  \
        inv = __builtin_amdgcn_rcpf(((z0 + z1) + (z2 + z3)) + z4);             \
    } else {                                                                   \
        /* WALK: weights carried, window = scattered regs + prefetched row */  \
        ptr = ptrW; base = baseW;                                              \
        nb0 = wnb0; nb1 = wnb1; nb2 = wnb2; nb3 = wnb3; nb4 = wnb4;            \
        p0 = wp0; p1 = wp1; p2 = wp2; p3 = wp3; p4 = wp4;                      \
        jt_nxt = jtW_pre;                                                      \
    }                                                                          \
    const f32x2 ctx = inv * (((nb0 * z0 + nb1 * z1) + (nb2 * z2 + nb3 * z3))   \
                             + nb4 * z4);                                      \
    f32x2 em; em[0] = (EC0); em[1] = (EC1);                                    \
    const f32x2 su = tanh2(em + cs * ctx + hid);                               \
    const f32x2 g  = su * inv;                                                 \
    const f32x2 m0v = nb0 + z0 * g, m1v = nb1 + z1 * g, m2v = nb2 + z2 * g,    \
                m3v = nb3 + z3 * g, m4v = nb4 + z4 * g;                        \
    *(f32x2*)p0 = m0v; *(f32x2*)p1 = m1v; *(f32x2*)p2 = m2v;                   \
    *(f32x2*)p3 = m3v; *(f32x2*)p4 = m4v;                                      \
    /* prep next walk candidate (reads after scatter; row base+3 untouched) */ \
    baseW = (base + 1) & 255;                                                  \
    ptrW  = ptr + 1.0f; if (ptrW >= 256.0f) ptrW -= 256.0f;                    \
    wnb0 = m1v; wnb1 = m2v; wnb2 = m3v; wnb3 = m4v;                            \
    wp0 = p1; wp1 = p2; wp2 = p3; wp3 = p4;                                    \
    wp4 = mem + (((base + 3) & 255) << 7) + 2 * l;                             \
    wnb4 = *(f32x2*)wp4;                                                       \
    jtW_pre = jd[baseW];                                                       \
    jt_cur  = jt_nxt;                                                          \
    /* reductions + LN + gate */                                               \
    float s1 = su[0] + su[1];                                                  \
    const f32x2 sq = su * su;  float s2 = sq[0] + sq[1];                       \
    const f32x2 sg = su * wg;  float s3 = sg[0] + sg[1];                       \
    wave_sum64_x3(s1, s2, s3);                                                 \
    const float mu   = s1 * (1.0f / En);                                       \
    const float var  = s2 * (1.0f / En) - mu * mu;                             \
    const float rstd = __builtin_amdgcn_rsqf(var + LN_EPS);                    \
    hid = (su - mu) * rstd * lnw + lnb;                                        \
    jl  = s3 + bgs;                                                            \
}

    for (int tb = 0; tb < 256; ++tb) {
        const int tp = tb + 2 > 255 ? 255 : tb + 2;
        float4 C0 = e40[tp << 7];
        float4 C1 = e41[tp << 7];
        SSTEP(A0.x, A1.x)
        SSTEP(A0.y, A1.y)
        SSTEP(A0.z, A1.z)
        SSTEP(A0.w, A1.w)
        A0 = B0; A1 = B1; B0 = C0; B1 = C1;
    }
#undef SSTEP

    // epilogue: logits = hid @ Wo^T + bo
    mem[l] = hid[0]; mem[64 + l] = hid[1];
    __syncthreads();
    const float4* w4 = (const float4*)(Wo + l * En);
    const float4* h4 = (const float4*)mem;
    float a0 = 0.f, a1 = 0.f, a2 = 0.f, a3 = 0.f;
    #pragma unroll
    for (int i = 0; i < En / 4; ++i) {
        float4 wv = w4[i]; float4 hv = h4[i];
        a0 += wv.x * hv.x; a1 += wv.y * hv.y; a2 += wv.z * hv.z; a3 += wv.w * hv.w;
    }
    out[b * NOUTn + l] = (a0 + a1) + (a2 + a3) + bo[l];
}

// ===========================================================================
// Fallback (ws too small for the 128 MiB emb buffer): round-1 kernel.
// ===========================================================================
#define LDS_FLOATS (Pn*En + 2*En + 2*In + Pn)
#define LDS_BYTES  (LDS_FLOATS * 4)

__global__ __launch_bounds__(192, 1)
void ring_kernel(const float* __restrict__ x,
                 const float* __restrict__ pointer_init,
                 const float* __restrict__ W_in,
                 const float* __restrict__ b_in,
                 const float* __restrict__ ln_w,
                 const float* __restrict__ ln_b,
                 const float* __restrict__ jump_dest,
                 const float* __restrict__ Wg,
                 const float* __restrict__ bg,
                 const float* __restrict__ cs_ptr,
                 const float* __restrict__ Wo,
                 const float* __restrict__ bo,
                 float* __restrict__ out)
{
    extern __shared__ float lds[];
    float* mem  = lds;
    float* embb = mem + Pn * En;
    float* xb   = embb + 2 * En;
    float* jd   = xb + 2 * In;

    const int b   = blockIdx.x;
    const int tid = threadIdx.x;

    for (int i = tid; i < Pn * En; i += 192) mem[i] = 0.0f;
    for (int i = tid; i < Pn;      i += 192) jd[i]  = jump_dest[i];

    const float* xrow = x + (size_t)b * Tn * In;
    if (tid < 64) {
        xb[tid]      = xrow[tid];
        xb[In + tid] = xrow[In + tid];
    }
    __syncthreads();

    if (tid >= 64) {
        const int p = tid - 64;
        float wr[In];
        {
            const float4* w4 = (const float4*)(W_in + p * In);
            #pragma unroll
            for (int i = 0; i < In / 4; ++i) {
                float4 v = w4[i];
                wr[4*i+0] = v.x; wr[4*i+1] = v.y; wr[4*i+2] = v.z; wr[4*i+3] = v.w;
            }
        }
        const float bi = b_in[p];
        {
            float acc = bi;
            #pragma unroll
            for (int i = 0; i < In; ++i) acc += wr[i] * xb[i];
            embb[p] = tanhf(acc);
        }
        __syncthreads();
        for (int t = 0; t < Tn; ++t) {
            if (t + 1 < Tn) {
                const float* xc = xb + ((t + 1) & 1) * In;
                float acc = bi;
                #pragma unroll
                for (int i = 0; i < In; ++i) acc += wr[i] * xc[i];
                embb[((t + 1) & 1) * En + p] = tanhf(acc);
            }
            __syncthreads();
        }
    } else {
        const int l = tid;
        const float lnw0 = ln_w[l],      lnw1 = ln_w[l + 64];
        const float lnb0 = ln_b[l],      lnb1 = ln_b[l + 64];
        const float wg0  = Wg[l],        wg1  = Wg[l + 64];
        const float bgs  = bg[0];
        const float cs   = 1.0f / (1.0f + expf(-cs_ptr[0]));
        float hid0 = 0.0f, hid1 = 0.0f;
        float ptr  = pointer_init[b];
        __syncthreads();

        for (int t = 0; t < Tn; ++t) {
            const bool do_stage = (t + 2 < Tn);
            float xs = 0.0f;
            if (do_stage) xs = xrow[(t + 2) * In + l];

            const float* embc = embb + (t & 1) * En;

            int base = (int)floorf(ptr);
            base = base < 0 ? 0 : (base > Pn - 1 ? Pn - 1 : base);
            int cur = (int)ptr;
            cur = cur < 0 ? 0 : (cur > Pn - 1 ? Pn - 1 : cur);
            const float jt = jd[cur];

            const float frac = ptr - (float)base;
            int   idx[5];
            float wgt[5];
            float mx = -3.4e38f;
            #pragma unroll
            for (int j = 0; j < 5; ++j) {
                idx[j] = (base + j - 2 + Pn) & (Pn - 1);
                float d = (float)(j - 2) - frac;
                float s = -(d * d) * 0.125f;
                wgt[j] = s;
                mx = fmaxf(mx, s);
            }
            float se = 0.0f;
            #pragma unroll
            for (int j = 0; j < 5; ++j) { float ez = expf(wgt[j] - mx); wgt[j] = ez; se += ez; }
            const float inv = 1.0f / se;

            float nb0[5], nb1[5];
            #pragma unroll
            for (int j = 0; j < 5; ++j) {
                nb0[j] = mem[idx[j] * En + l];
                nb1[j] = mem[idx[j] * En + 64 + l];
            }
            float ctx0 = 0.0f, ctx1 = 0.0f;
            #pragma unroll
            for (int j = 0; j < 5; ++j) {
                const float w = wgt[j] * inv; wgt[j] = w;
                ctx0 += w * nb0[j];
                ctx1 += w * nb1[j];
            }

            const float su0 = tanhf(embc[l]      + cs * ctx0 + hid0);
            const float su1 = tanhf(embc[l + 64] + cs * ctx1 + hid1);

            #pragma unroll
            for (int j = 0; j < 5; ++j) {
                mem[idx[j] * En + l]      = nb0[j] + wgt[j] * su0;
                mem[idx[j] * En + 64 + l] = nb1[j] + wgt[j] * su1;
            }

            float s1 = su0 + su1;
            float s2 = su0 * su0 + su1 * su1;
            float s3 = su0 * wg0 + su1 * wg1;
            #pragma unroll
            for (int off = 32; off > 0; off >>= 1) {
                s1 += __shfl_xor(s1, off, 64);
                s2 += __shfl_xor(s2, off, 64);
                s3 += __shfl_xor(s3, off, 64);
            }

            const float mu   = s1 * (1.0f / En);
            const float var  = s2 * (1.0f / En) - mu * mu;
            const float rstd = rsqrtf(var + LN_EPS);
            hid0 = (su0 - mu) * rstd * lnw0 + lnb0;
            hid1 = (su1 - mu) * rstd * lnw1 + lnb1;

            const float jl = s3 + bgs;
            float walk = ptr + 1.0f;
            if (walk >= 256.0f) walk -= 256.0f;
            ptr = (jl > 0.0f) ? jt : walk;

            if (do_stage) xb[(t & 1) * In + l] = xs;
            __syncthreads();
        }
        embb[l]      = hid0;
        embb[l + 64] = hid1;
    }
    __syncthreads();

    if (tid < NOUTn) {
        const float* wrow = Wo + tid * En;
        float acc = bo[tid];
        #pragma unroll 4
        for (int e = 0; e < En; ++e) acc += embb[e] * wrow[e];
        out[b * NOUTn + tid] = acc;
    }
}

extern "C" void kernel_launch(void* const* d_in, const int* in_sizes, int n_in,
                              void* d_out, int out_size, void* d_ws, size_t ws_size,
                              hipStream_t stream) {
    const float* x            = (const float*)d_in[0];
    const float* pointer_init = (const float*)d_in[1];
    const float* W_in         = (const float*)d_in[2];
    const float* b_in         = (const float*)d_in[3];
    const float* ln_w         = (const float*)d_in[4];
    const float* ln_b         = (const float*)d_in[5];
    const float* jump_dest    = (const float*)d_in[6];
    const float* Wg           = (const float*)d_in[7];
    const float* bg           = (const float*)d_in[8];
    const float* cs           = (const float*)d_in[9];
    const float* Wo           = (const float*)d_in[10];
    const float* bo           = (const float*)d_in[11];
    float* out = (float*)d_out;

    const size_t emb_bytes = (size_t)Bn * Tn * En * sizeof(float);   // 128 MiB

    if (ws_size >= emb_bytes) {
        float* emb4 = (float*)d_ws;
        embgemm_kernel<<<Bn * 8, 256, 0, stream>>>(x, W_in, b_in, emb4);
        (void)hipFuncSetAttribute((const void*)scan4_kernel,
                                  hipFuncAttributeMaxDynamicSharedMemorySize, LDSG_BYTES);
        scan4_kernel<<<Bn, 64, LDSG_BYTES, stream>>>(
            emb4, pointer_init, ln_w, ln_b, jump_dest, Wg, bg, cs, Wo, bo, out);
    } else {
        (void)hipFuncSetAttribute((const void*)ring_kernel,
                                  hipFuncAttributeMaxDynamicSharedMemorySize, LDS_BYTES);
        ring_kernel<<<Bn, 192, LDS_BYTES, stream>>>(
            x, pointer_init, W_in, b_in, ln_w, ln_b, jump_dest, Wg, bg, cs, Wo, bo, out);
    }
}